// Round 4
// baseline (69.157 us; speedup 1.0000x reference)
//
#include <hip/hip_runtime.h>
#include <hip/hip_fp16.h>
#include <cmath>

#define BB 4
#define HH 64
#define WW 64
#define COLS 65
#define TA 0                       // 64 x COLS : t-buffer / packed-coords / agg / h1
#define OFFB (64*COLS)             // 104 x COLS : raw offsets
#define TB OFFB                    // 64 x COLS : pc output (overlaps OFFB, live later)
#define MB (OFFB + 104*COLS)       // 53 x COLS : mask -> mod
#define POOL (MB + 53*COLS)        // 14365 floats = 57460 B

// ---------------- NCHW -> NHWC transpose (LDS tiled) ----------------
__global__ __launch_bounds__(256) void transpose_kernel(const float* __restrict__ x,
                                                        float* __restrict__ xt) {
    int bid = blockIdx.x;
    int b = bid >> 6, y = bid & 63;
    __shared__ float tile[64][65];
    const float* xp = x + ((size_t)b * 64 * HH + y) * WW;
    #pragma unroll
    for (int k = 0; k < 16; ++k) {
        int idx = threadIdx.x + (k << 8);
        int c = idx >> 6, w = idx & 63;
        tile[c][w] = xp[(size_t)c * HH * WW + w];
    }
    __syncthreads();
    float* op = xt + ((size_t)(b * HH + y) * WW) * 64;
    #pragma unroll
    for (int k = 0; k < 16; ++k) {
        int idx = threadIdx.x + (k << 8);
        int w = idx >> 6, c = idx & 63;
        op[(size_t)w * 64 + c] = tile[c][w];
    }
}

// pointwise GEMM helper: lane = pixel, wave owns RPW consecutive output rows.
template<int RPW>
__device__ inline void pw_gemm(float* P, int lane, int o0, int R,
                               const float* __restrict__ W, const float* __restrict__ Bv,
                               int dbase) {
    int oc[RPW];
    float acc[RPW];
    #pragma unroll
    for (int r = 0; r < RPW; ++r) {
        oc[r] = min(o0 + r, R - 1);
        acc[r] = Bv[oc[r]];
    }
    #pragma unroll 8
    for (int k = 0; k < 64; ++k) {
        float v = P[TA + k * COLS + lane];
        #pragma unroll
        for (int r = 0; r < RPW; ++r)
            acc[r] = fmaf(W[oc[r] * 64 + k], v, acc[r]);
    }
    #pragma unroll
    for (int r = 0; r < RPW; ++r)
        if (o0 + r < R) P[dbase + (o0 + r) * COLS + lane] = acc[r];
}

// ---------------- fused main: 1 block (16 waves, 1024 thr) per image row ----------------
__global__ __launch_bounds__(1024, 4) void crossd_main(
    const float* __restrict__ xt, const float* __restrict__ x,
    const float* __restrict__ p_n,
    const float* __restrict__ dwf_w, const float* __restrict__ dwf_b,
    const float* __restrict__ pwf_w, const float* __restrict__ pwf_b,
    const float* __restrict__ dwc_w, const float* __restrict__ dwc_b,
    const float* __restrict__ pwc_w, const float* __restrict__ pwc_b,
    const float* __restrict__ dwm_w, const float* __restrict__ dwm_b,
    const float* __restrict__ pwm_w, const float* __restrict__ pwm_b,
    const float* __restrict__ pc_w, const float* __restrict__ pc_b,
    const float* __restrict__ w1, const float* __restrict__ b1,
    const float* __restrict__ w2, const float* __restrict__ b2,
    float* __restrict__ out)
{
    __shared__ float P[POOL];
    const int tid  = threadIdx.x;
    const int lane = tid & 63;
    const int wv   = __builtin_amdgcn_readfirstlane(tid >> 6);   // 0..15
    const int b = blockIdx.x >> 6, y = blockIdx.x & 63;
    const float* xtb = xt + (size_t)b * (HH * WW * 64);

    // ---- fused depthwise 3x3 (3 branches share loads); wave owns 4 px, lane = ch ----
    float tc_r[4], tm_r[4];
    {
        const int c = lane;
        float wf9[9], wc9[9], wm9[9];
        #pragma unroll
        for (int k9 = 0; k9 < 9; ++k9) {
            wf9[k9] = dwf_w[c * 9 + k9];
            wc9[k9] = dwc_w[c * 9 + k9];
            wm9[k9] = dwm_w[c * 9 + k9];
        }
        const float bf = dwf_b[c], bc = dwc_b[c], bm = dwm_b[c];
        #pragma unroll
        for (int i = 0; i < 4; ++i) {
            const int px = wv * 4 + i;
            float af = bf, ac = bc, am = bm;
            #pragma unroll
            for (int dy = 0; dy < 3; ++dy) {
                int yy = y + dy - 1;
                if (yy < 0 || yy >= HH) continue;
                #pragma unroll
                for (int dx = 0; dx < 3; ++dx) {
                    int xx = px + dx - 1;
                    if (xx < 0 || xx >= WW) continue;
                    float v = xtb[(size_t)((yy << 6) + xx) * 64 + c];
                    int k = dy * 3 + dx;
                    af = fmaf(v, wf9[k], af);
                    ac = fmaf(v, wc9[k], ac);
                    am = fmaf(v, wm9[k], am);
                }
            }
            P[TA + c * COLS + px] = af;
            tc_r[i] = ac; tm_r[i] = am;
        }
    }
    __syncthreads();
    pw_gemm<2>(P, lane, wv * 2, 32, pwf_w, pwf_b, OFFB);             // f: 32 rows
    __syncthreads();
    #pragma unroll
    for (int i = 0; i < 4; ++i) P[TA + lane * COLS + wv * 4 + i] = tc_r[i];
    __syncthreads();
    pw_gemm<5>(P, lane, wv * 5, 72, pwc_w, pwc_b, OFFB + 32 * COLS); // c: 72 rows
    __syncthreads();
    #pragma unroll
    for (int i = 0; i < 4; ++i) P[TA + lane * COLS + wv * 4 + i] = tm_r[i];
    __syncthreads();
    pw_gemm<4>(P, lane, wv * 4, 53, pwm_w, pwm_b, MB);               // m: 53 rows
    __syncthreads();

    // ---- gated softmax over 52 scores: lane = n, wave owns 4 px ----
    #pragma unroll
    for (int i = 0; i < 4; ++i) {
        const int px = wv * 4 + i;
        const float sp = P[MB + 52 * COLS + px];
        float z = -1e30f;
        if (lane < 52) {
            float s  = P[MB + lane * COLS + px];
            float sg = 1.0f / (1.0f + __expf(-(s - sp) * 10.0f));
            z = s + __logf(sg + 1e-10f);
        }
        float mx = z;
        #pragma unroll
        for (int d = 32; d >= 1; d >>= 1) mx = fmaxf(mx, __shfl_xor(mx, d));
        float e = (lane < 52) ? __expf(z - mx) : 0.0f;
        float sm = e;
        #pragma unroll
        for (int d = 32; d >= 1; d >>= 1) sm += __shfl_xor(sm, d);
        if (lane < 52) P[MB + lane * COLS + px] = e / sm;
    }
    __syncthreads();

    // ---- sampling: chunked packed precompute (in TA) + float4 gather ----
    const int sub = lane >> 4;          // 0..3  (pixel within wave's quad)
    const int c4  = lane & 15;          // channel quad
    const int spx = wv * 4 + sub;
    const float4* xt4 = reinterpret_cast<const float4*>(xtb);
    uint32_t* PKu = reinterpret_cast<uint32_t*>(&P[TA]);
    float4 agg = make_float4(0.f, 0.f, 0.f, 0.f);

    for (int nbase = 0; nbase < 52; nbase += 16) {
        const int ncnt = (nbase + 16 <= 52) ? 16 : (52 - nbase);   // 16,16,16,4
        {   // precompute: one (n,px) item per thread
            const int nn = tid >> 6, ppx = tid & 63;
            if (nn < ncnt) {
                const int n = nbase + nn;
                float sx = (float)ppx + p_n[n]      + P[OFFB + n * COLS + ppx];
                float sy = (float)y   + p_n[52 + n] + P[OFFB + (52 + n) * COLS + ppx];
                float mo = P[MB + n * COLS + ppx];
                float x0f = floorf(sx), y0f = floorf(sy);
                float wx1 = sx - x0f, wy1 = sy - y0f;
                float wx0 = 1.0f - wx1, wy0 = 1.0f - wy1;
                int x0 = (int)x0f, y0 = (int)y0f;
                int xi0 = min(max(x0, 0), 63), xi1 = min(max(x0 + 1, 0), 63);
                int yi0 = min(max(y0, 0), 63), yi1 = min(max(y0 + 1, 0), 63);
                bool vx0 = (x0 >= 0)  & (x0 <= 63);
                bool vx1 = (x0 >= -1) & (x0 <= 62);
                bool vy0 = (y0 >= 0)  & (y0 <= 63);
                bool vy1 = (y0 >= -1) & (y0 <= 62);
                float m00 = (vy0 & vx0) ? mo * wy0 * wx0 : 0.0f;
                float m01 = (vy0 & vx1) ? mo * wy0 * wx1 : 0.0f;
                float m10 = (vy1 & vx0) ? mo * wy1 * wx0 : 0.0f;
                float m11 = (vy1 & vx1) ? mo * wy1 * wx1 : 0.0f;
                uint32_t a00 = (uint32_t)((yi0 << 6) | xi0);
                uint32_t a11 = (uint32_t)((yi1 << 6) | xi1);
                __half2 hA = __floats2half2_rn(m00, m01);
                __half2 hB = __floats2half2_rn(m10, m11);
                const int base = (nn * 64 + ppx) * 4;
                PKu[base + 0] = a00 | (a11 << 16);
                PKu[base + 1] = *reinterpret_cast<uint32_t*>(&hA);
                PKu[base + 2] = *reinterpret_cast<uint32_t*>(&hB);
            }
        }
        __syncthreads();
        for (int j0 = 0; j0 < ncnt; j0 += 4) {
            #pragma unroll
            for (int j = 0; j < 4; ++j) {
                uint4 pk = reinterpret_cast<const uint4*>(PKu)[(j0 + j) * 64 + spx];
                uint32_t a00 = pk.x & 0xFFFFu, a11 = pk.x >> 16;
                uint32_t a01 = (a00 & ~63u) | (a11 & 63u);
                uint32_t a10 = (a11 & ~63u) | (a00 & 63u);
                __half2 hA = *reinterpret_cast<__half2*>(&pk.y);
                __half2 hB = *reinterpret_cast<__half2*>(&pk.z);
                float m00 = __low2float(hA), m01 = __high2float(hA);
                float m10 = __low2float(hB), m11 = __high2float(hB);
                float4 s00 = xt4[(a00 << 4) + c4];
                float4 s01 = xt4[(a01 << 4) + c4];
                float4 s10 = xt4[(a10 << 4) + c4];
                float4 s11 = xt4[(a11 << 4) + c4];
                agg.x = fmaf(m00, s00.x, agg.x); agg.y = fmaf(m00, s00.y, agg.y);
                agg.z = fmaf(m00, s00.z, agg.z); agg.w = fmaf(m00, s00.w, agg.w);
                agg.x = fmaf(m01, s01.x, agg.x); agg.y = fmaf(m01, s01.y, agg.y);
                agg.z = fmaf(m01, s01.z, agg.z); agg.w = fmaf(m01, s01.w, agg.w);
                agg.x = fmaf(m10, s10.x, agg.x); agg.y = fmaf(m10, s10.y, agg.y);
                agg.z = fmaf(m10, s10.z, agg.z); agg.w = fmaf(m10, s10.w, agg.w);
                agg.x = fmaf(m11, s11.x, agg.x); agg.y = fmaf(m11, s11.y, agg.y);
                agg.z = fmaf(m11, s11.z, agg.z); agg.w = fmaf(m11, s11.w, agg.w);
            }
        }
        __syncthreads();
    }

    // PK (TA) fully consumed; store agg transposed [c][px]
    P[TA + (c4 * 4 + 0) * COLS + spx] = agg.x;
    P[TA + (c4 * 4 + 1) * COLS + spx] = agg.y;
    P[TA + (c4 * 4 + 2) * COLS + spx] = agg.z;
    P[TA + (c4 * 4 + 3) * COLS + spx] = agg.w;
    __syncthreads();

    // ---- pc 1x1: TA -> TB ----
    pw_gemm<4>(P, lane, wv * 4, 64, pc_w, pc_b, TB);
    __syncthreads();

    // ---- mlp1 (relu): TB -> TA ----
    {
        const int o0 = wv * 4;
        float acc[4];
        #pragma unroll
        for (int r = 0; r < 4; ++r) acc[r] = b1[o0 + r];
        #pragma unroll 8
        for (int k = 0; k < 64; ++k) {
            float v = P[TB + k * COLS + lane];
            #pragma unroll
            for (int r = 0; r < 4; ++r) acc[r] = fmaf(w1[(o0 + r) * 64 + k], v, acc[r]);
        }
        #pragma unroll
        for (int r = 0; r < 4; ++r) P[TA + (o0 + r) * COLS + lane] = fmaxf(acc[r], 0.0f);
    }
    __syncthreads();

    // ---- mlp2 + residual + coalesced NCHW store ----
    {
        const int o0 = wv * 4;
        float acc[4];
        #pragma unroll
        for (int r = 0; r < 4; ++r) acc[r] = b2[o0 + r];
        #pragma unroll 8
        for (int k = 0; k < 64; ++k) {
            float v = P[TA + k * COLS + lane];
            #pragma unroll
            for (int r = 0; r < 4; ++r) acc[r] = fmaf(w2[(o0 + r) * 64 + k], v, acc[r]);
        }
        #pragma unroll
        for (int r = 0; r < 4; ++r) {
            int o = o0 + r;
            size_t idx = (((size_t)b * 64 + o) * 64 + y) * 64 + lane;
            out[idx] = acc[r] + x[idx];
        }
    }
}

extern "C" void kernel_launch(void* const* d_in, const int* in_sizes, int n_in,
                              void* d_out, int out_size, void* d_ws, size_t ws_size,
                              hipStream_t stream) {
    const float* x     = (const float*)d_in[0];
    const float* p_n   = (const float*)d_in[1];
    const float* dwf_w = (const float*)d_in[2];
    const float* dwf_b = (const float*)d_in[3];
    const float* pwf_w = (const float*)d_in[4];
    const float* pwf_b = (const float*)d_in[5];
    const float* dwc_w = (const float*)d_in[6];
    const float* dwc_b = (const float*)d_in[7];
    const float* pwc_w = (const float*)d_in[8];
    const float* pwc_b = (const float*)d_in[9];
    const float* dwm_w = (const float*)d_in[10];
    const float* dwm_b = (const float*)d_in[11];
    const float* pwm_w = (const float*)d_in[12];
    const float* pwm_b = (const float*)d_in[13];
    const float* pc_w  = (const float*)d_in[14];
    const float* pc_b  = (const float*)d_in[15];
    const float* w1    = (const float*)d_in[16];
    const float* b1    = (const float*)d_in[17];
    const float* w2    = (const float*)d_in[18];
    const float* b2    = (const float*)d_in[19];

    float* xt   = (float*)d_ws;       // 4 MB NHWC copy of x
    float* outp = (float*)d_out;

    hipLaunchKernelGGL(transpose_kernel, dim3(BB * HH), dim3(256), 0, stream, x, xt);
    hipLaunchKernelGGL(crossd_main, dim3(BB * HH), dim3(1024), 0, stream,
                       xt, x, p_n,
                       dwf_w, dwf_b, pwf_w, pwf_b,
                       dwc_w, dwc_b, pwc_w, pwc_b,
                       dwm_w, dwm_b, pwm_w, pwm_b,
                       pc_w, pc_b, w1, b1, w2, b2, outp);
}